// Round 1
// 829.232 us; speedup vs baseline: 1.4455x; 1.4455x over previous
//
#include <hip/hip_runtime.h>
#include <math.h>

#define N_TOK 8192
#define DIM 2048
#define HDIM 2048
#define ODIM 2048
#define NEXP 8
#define CAPACITY 2560

typedef __bf16 bf16x8 __attribute__((ext_vector_type(8)));
typedef float f32x4 __attribute__((ext_vector_type(4)));

__device__ __forceinline__ void async16(const void* g, void* l) {
  __builtin_amdgcn_global_load_lds(
      (const __attribute__((address_space(1))) void*)g,
      (__attribute__((address_space(3))) void*)l, 16, 0, 0);
}

// ---------------- router: 1 wave per token; also emits x as bf16 ----------
__global__ __launch_bounds__(64) void router_kernel(
    const float* __restrict__ x, const float* __restrict__ gate_w,
    const float* __restrict__ gate_b, const float* __restrict__ temp,
    float* __restrict__ probs, int* __restrict__ sel, float* __restrict__ rwv,
    __bf16* __restrict__ xb) {
  int t = blockIdx.x;
  int lane = threadIdx.x;
  const float* xr = x + (size_t)t * DIM;
  __bf16* xbr = xb + (size_t)t * DIM;
  float part[NEXP];
#pragma unroll
  for (int e = 0; e < NEXP; e++) part[e] = 0.f;
  for (int k = lane; k < DIM; k += 64) {
    float xv = xr[k];
    xbr[k] = (__bf16)xv;
    const float* gw = gate_w + (size_t)k * NEXP;
#pragma unroll
    for (int e = 0; e < NEXP; e++) part[e] += xv * gw[e];
  }
#pragma unroll
  for (int e = 0; e < NEXP; e++) {
    float v = part[e];
#pragma unroll
    for (int off = 32; off > 0; off >>= 1) v += __shfl_down(v, off);
    part[e] = v;
  }
  if (lane == 0) {
    float it = 1.0f / fabsf(temp[0]);
    float lg[NEXP];
    float m = -1e30f;
#pragma unroll
    for (int e = 0; e < NEXP; e++) {
      lg[e] = (part[e] + gate_b[e]) * it;
      m = fmaxf(m, lg[e]);
    }
    float s = 0.f;
    float p[NEXP];
#pragma unroll
    for (int e = 0; e < NEXP; e++) { p[e] = expf(lg[e] - m); s += p[e]; }
    float inv_s = 1.f / s;
#pragma unroll
    for (int e = 0; e < NEXP; e++) { p[e] *= inv_s; probs[(size_t)t * NEXP + e] = p[e]; }
    int e1 = 0;
#pragma unroll
    for (int e = 1; e < NEXP; e++) if (p[e] > p[e1]) e1 = e;
    int e2 = -1;
#pragma unroll
    for (int e = 0; e < NEXP; e++) {
      if (e == e1) continue;
      if (e2 < 0 || p[e] > p[e2]) e2 = e;
    }
    float s2 = p[e1] + p[e2];
    sel[t * 2 + 0] = e1;
    sel[t * 2 + 1] = e2;
    rwv[t * 2 + 0] = p[e1] / s2;
    rwv[t * 2 + 1] = p[e2] / s2;
  }
}

// ---------------- aux loss + per-expert assignment counts ----------------
__global__ __launch_bounds__(256) void aux_kernel(
    const float* __restrict__ probs, const int* __restrict__ sel,
    float* __restrict__ aux_out, int* __restrict__ cnt_assign,
    int* __restrict__ list_cnt) {
  int tid = threadIdx.x;
  float lps[NEXP];
  int lc[NEXP];
#pragma unroll
  for (int e = 0; e < NEXP; e++) { lps[e] = 0.f; lc[e] = 0; }
  for (int t = tid; t < N_TOK; t += 256) {
    const float* pr = probs + (size_t)t * NEXP;
#pragma unroll
    for (int e = 0; e < NEXP; e++) lps[e] += pr[e];
  }
  for (int j = tid; j < N_TOK * 2; j += 256) lc[sel[j]]++;
  __shared__ float sps[NEXP][256];
  __shared__ int scs[NEXP][256];
#pragma unroll
  for (int e = 0; e < NEXP; e++) { sps[e][tid] = lps[e]; scs[e][tid] = lc[e]; }
  __syncthreads();
  for (int off = 128; off > 0; off >>= 1) {
    if (tid < off) {
#pragma unroll
      for (int e = 0; e < NEXP; e++) {
        sps[e][tid] += sps[e][tid + off];
        scs[e][tid] += scs[e][tid + off];
      }
    }
    __syncthreads();
  }
  if (tid < NEXP) {
    cnt_assign[tid] = scs[tid][0];
    list_cnt[tid] = 0;
  }
  if (tid == 0) {
    float ps[NEXP];
    int cs[NEXP];
#pragma unroll
    for (int e = 0; e < NEXP; e++) { ps[e] = sps[e][0]; cs[e] = scs[e][0]; }
    float balance = 0.f;
#pragma unroll
    for (int e = 0; e < NEXP; e++)
      balance += (ps[e] / (float)N_TOK) * ((float)cs[e] / (float)N_TOK);
    balance *= (float)NEXP;
    float meanimp = 0.f;
#pragma unroll
    for (int e = 0; e < NEXP; e++) meanimp += ps[e];
    meanimp /= (float)NEXP;
    float var = 0.f;
#pragma unroll
    for (int e = 0; e < NEXP; e++) { float d = ps[e] - meanimp; var += d * d; }
    var /= (float)(NEXP - 1);
    float cv = sqrtf(var) / (meanimp + 1e-10f);
    aux_out[0] = balance + 0.01f * cv;
  }
}

// ---------------- weight transpose + convert: [K][N] f32 -> [N][K] bf16 ----
__global__ __launch_bounds__(256) void transpose_cvt_kernel(
    const float* __restrict__ w1, const float* __restrict__ w2,
    ushort* __restrict__ wt_all) {
  int z = blockIdx.z;
  const float* src = (z < 8) ? (w1 + (size_t)z * DIM * HDIM)
                             : (w2 + (size_t)(z - 8) * HDIM * ODIM);
  ushort* dst = wt_all + (size_t)z * 2048 * 2048;
  __shared__ float tile[64][68];
  int tid = threadIdx.x;
  int k0 = blockIdx.x * 64;
  int n0 = blockIdx.y * 64;
  int tr = tid >> 4;
  int tc = (tid & 15) * 4;
#pragma unroll
  for (int i = 0; i < 4; i++) {
    int r = tr + i * 16;
    float4 v = *(const float4*)(src + (size_t)(k0 + r) * 2048 + n0 + tc);
    *(float4*)&tile[r][tc] = v;
  }
  __syncthreads();
#pragma unroll
  for (int i = 0; i < 4; i++) {
    int n = tr + i * 16;
    __bf16 o[4];
#pragma unroll
    for (int j = 0; j < 4; j++) o[j] = (__bf16)tile[tc + j][n];
    *(ushort4*)(dst + (size_t)(n0 + n) * 2048 + k0 + tc) = *(const ushort4*)o;
  }
}

// ---------------- capacity-exact expert list build ----------------
__global__ __launch_bounds__(256) void build_lists(
    const int* __restrict__ sel, const float* __restrict__ rwv,
    const int* __restrict__ cnt_assign, int* __restrict__ list_cnt,
    int* __restrict__ etok, int* __restrict__ pos) {
  int j = blockIdx.x * blockDim.x + threadIdx.x;
  if (j >= N_TOK * 2) return;
  int e = sel[j];
  float w = rwv[j];
  bool keep = true;
  if (cnt_assign[e] > CAPACITY) {
    int rank = 0;
    for (int j2 = 0; j2 < N_TOK * 2; j2++) {
      if (sel[j2] == e) {
        float w2 = rwv[j2];
        if (w2 > w || (w2 == w && j2 < j)) rank++;
      }
    }
    keep = (rank < CAPACITY);
  }
  if (keep) {
    int slot = atomicAdd(&list_cnt[e], 1);
    etok[(size_t)e * CAPACITY + slot] = j >> 1;
    pos[j] = e * CAPACITY + slot;
  } else {
    pos[j] = -1;
  }
}

// ================= 8-phase 256x256 MFMA FFN (T1+T2+T3+T4+T5) =================
// Tile 256x256, BK=64, 8 waves (2Mx4N), per-wave output 128x64 (8 m-tiles x 4
// n-tiles). LDS 128KB: [A|B][dbuf 2][half 2][128 rows][64 k] bf16, k-unit
// XOR-swizzled (kp = kl ^ (row&7)) via pre-swizzled GLOBAL source + swizzled
// ds_read (linear global_load_lds dest — rule #21).
// Stage ledger (one half-tile per phase, staged the phase AFTER its last read):
//   ph0: buf1.A1<-2j+1  ph1: buf0.B0<-2j+2  ph2: buf0.B1<-2j+2  ph3: buf0.A0<-2j+2
//   ph4: buf0.A1<-2j+2  ph5: buf1.B0<-2j+3  ph6: buf1.B1<-2j+3  ph7: buf1.A0<-2j+3
// vmcnt(6) at end of ph3/ph7: 14 outstanding loads -> drain oldest 8 (exactly
// through the halves needed after the next barrier), 3 half-tiles stay in flight.

#define BAR() asm volatile("s_barrier" ::: "memory")
#define VMCNT6() asm volatile("s_waitcnt vmcnt(6)" ::: "memory")

#define STAGE_A(d, h, t)                                                    \
  do {                                                                      \
    int _k0 = ((t) & 31) * 64;                                              \
    async16(gaP[(h) * 2 + 0] + _k0, dstA + (d) * 32768 + (h) * 16384);      \
    async16(gaP[(h) * 2 + 1] + _k0, dstA + (d) * 32768 + (h) * 16384 + 8192); \
  } while (0)

#define STAGE_B(d, h, t)                                                    \
  do {                                                                      \
    int _k0 = ((t) & 31) * 64;                                              \
    async16(gbP[(h) * 2 + 0] + _k0, dstB + (d) * 32768 + (h) * 16384);      \
    async16(gbP[(h) * 2 + 1] + _k0, dstB + (d) * 32768 + (h) * 16384 + 8192); \
  } while (0)

#define LOAD_B(d)                                                           \
  do {                                                                      \
    _Pragma("unroll") for (int nt = 0; nt < 4; nt++) {                      \
      bfr[nt][0] = *(const bf16x8*)(smem + (d) * 32768 + boff + nt * 2048 + kx0); \
      bfr[nt][1] = *(const bf16x8*)(smem + (d) * 32768 + boff + nt * 2048 + kx1); \
    }                                                                       \
  } while (0)

#define LOAD_A(d, q)                                                        \
  do {                                                                      \
    _Pragma("unroll") for (int s = 0; s < 2; s++) {                         \
      af[s][0] = *(const bf16x8*)(smem + (d) * 32768 + ((q) >> 1) * 16384 + \
                                  ((q) & 1) * 8192 + aoff + s * 2048 + kx0); \
      af[s][1] = *(const bf16x8*)(smem + (d) * 32768 + ((q) >> 1) * 16384 + \
                                  ((q) & 1) * 8192 + aoff + s * 2048 + kx1); \
    }                                                                       \
  } while (0)

#define MFMA_PH(q)                                                          \
  do {                                                                      \
    __builtin_amdgcn_s_setprio(1);                                          \
    _Pragma("unroll") for (int s = 0; s < 2; s++)                           \
    _Pragma("unroll") for (int nt = 0; nt < 4; nt++) {                      \
      acc[(q) * 2 + s][nt] = __builtin_amdgcn_mfma_f32_16x16x32_bf16(       \
          af[s][0], bfr[nt][0], acc[(q) * 2 + s][nt], 0, 0, 0);             \
      acc[(q) * 2 + s][nt] = __builtin_amdgcn_mfma_f32_16x16x32_bf16(       \
          af[s][1], bfr[nt][1], acc[(q) * 2 + s][nt], 0, 0, 0);             \
    }                                                                       \
    __builtin_amdgcn_s_setprio(0);                                          \
  } while (0)

template <bool GATHER, bool RELU>
__global__ __launch_bounds__(512, 2) void mfma_ffn_8ph(
    const __bf16* __restrict__ Abase, const __bf16* __restrict__ Wt,
    const float* __restrict__ bias, const int* __restrict__ etok,
    const int* __restrict__ list_cnt, __bf16* __restrict__ Out) {
  __shared__ __align__(16) char smem[131072];

  // XCD swizzle: 640 blocks, id%8 = XCD -> XCD k owns 80 consecutive tiles
  // = exactly one expert (10 row-blocks x 8 col-blocks).
  int id = blockIdx.x;
  int nid = (id & 7) * 80 + (id >> 3);
  int bx = nid % 10;
  int by = (nid / 10) & 7;
  int e = nid / 80;
  int cnt = list_cnt[e];
  int row0 = bx * 256;
  if (row0 >= cnt) return;  // block-uniform: whole block exits before barriers
  int col0 = by * 256;

  const __bf16* We = Wt + (size_t)e * DIM * DIM;
  const int* etok_e = etok + e * CAPACITY;
  const float* bias_e = bias + (size_t)e * DIM;
  __bf16* OutE = Out + (size_t)e * CAPACITY * DIM;

  int tid = threadIdx.x;
  int rA = tid >> 3;  // 0..63: row within a 64-row stage group
  int kp = tid & 7;   // physical 16B k-unit this thread fills

  // Precompute the 4 gather row pointers per operand (one per half x group),
  // with the inverse swizzle folded into the global source address.
  const __bf16* gaP[4];
  const __bf16* gbP[4];
#pragma unroll
  for (int h = 0; h < 2; h++) {
#pragma unroll
    for (int g = 0; g < 2; g++) {
      int r = h * 128 + g * 64 + rA;
      int kl = kp ^ (r & 7);  // logical k-unit living in physical slot kp
      int arow = row0 + r;
      const __bf16* ap;
      if (GATHER) {
        int tok = (arow < cnt) ? etok_e[arow] : 0;
        ap = Abase + (size_t)tok * DIM;
      } else {
        ap = Abase + (size_t)e * CAPACITY * DIM + (size_t)arow * DIM;
      }
      gaP[h * 2 + g] = ap + kl * 8;
      gbP[h * 2 + g] = We + (size_t)(col0 + r) * DIM + kl * 8;
    }
  }
  char* dstA = smem + tid * 16;          // A region: [0, 64KB)
  char* dstB = smem + 65536 + tid * 16;  // B region: [64KB, 128KB)

  int wid = tid >> 6, lane = tid & 63;
  int wm = wid >> 2, wn = wid & 3;
  int lm = lane & 15, lg = lane >> 4;
  int kx0 = ((0 * 4 + lg) ^ (lm & 7)) * 16;  // swizzled k-unit byte, ks=0
  int kx1 = ((1 * 4 + lg) ^ (lm & 7)) * 16;  // ks=1
  int aoff = (wm * 32 + lm) * 128;
  int boff = 65536 + (wn >> 1) * 16384 + ((wn & 1) * 64 + lm) * 128;

  f32x4 acc[8][4] = {};
  bf16x8 bfr[4][2];
  bf16x8 af[2][2];

  // Prologue: prime pipeline exactly like steady-state ph1..ph7 of iter -1.
  STAGE_B(0, 0, 0); STAGE_B(0, 1, 0); STAGE_A(0, 0, 0); STAGE_A(0, 1, 0);
  STAGE_B(1, 0, 1); STAGE_B(1, 1, 1); STAGE_A(1, 0, 1);
  VMCNT6();  // 14 outstanding -> drain tile0's 8; 3 half-tiles stay in flight
  BAR();

#pragma unroll 1
  for (int j = 0; j < 16; j++) {
    int t1 = 2 * j + 1, t2 = 2 * j + 2, t3 = 2 * j + 3;  // stages wrap &31 (tail)
    // ---- K-tile 2j from buf0 ----
    LOAD_B(0); LOAD_A(0, 0); STAGE_A(1, 1, t1);
    BAR(); MFMA_PH(0); BAR();
    LOAD_A(0, 1); STAGE_B(0, 0, t2);
    BAR(); MFMA_PH(1); BAR();
    LOAD_A(0, 2); STAGE_B(0, 1, t2);
    BAR(); MFMA_PH(2); BAR();
    LOAD_A(0, 3); STAGE_A(0, 0, t2);
    VMCNT6();
    BAR(); MFMA_PH(3); BAR();
    // ---- K-tile 2j+1 from buf1 ----
    LOAD_B(1); LOAD_A(1, 0); STAGE_A(0, 1, t2);
    BAR(); MFMA_PH(0); BAR();
    LOAD_A(1, 1); STAGE_B(1, 0, t3);
    BAR(); MFMA_PH(1); BAR();
    LOAD_A(1, 2); STAGE_B(1, 1, t3);
    BAR(); MFMA_PH(2); BAR();
    LOAD_A(1, 3); STAGE_A(1, 0, t3);
    VMCNT6();
    BAR(); MFMA_PH(3); BAR();
  }

  // Drain stale wrapped prefetches before reusing LDS for the epilogue.
  asm volatile("s_waitcnt vmcnt(0)" ::: "memory");
  __syncthreads();

  float bcol[4];
#pragma unroll
  for (int nt = 0; nt < 4; nt++) bcol[nt] = bias_e[col0 + wn * 64 + nt * 16 + lm];

  __bf16* T = (__bf16*)smem;  // [128][268] bf16 per pass (68.6KB)
#pragma unroll
  for (int p = 0; p < 2; p++) {
    if (p) __syncthreads();
#pragma unroll
    for (int u = 0; u < 4; u++) {
      int am = 4 * p + u;
      int rbase = ((am >> 1) & 1) * 64 + wm * 32 + (am & 1) * 16 + lg * 4;
#pragma unroll
      for (int nt = 0; nt < 4; nt++) {
        int col = wn * 64 + nt * 16 + lm;
#pragma unroll
        for (int reg = 0; reg < 4; reg++) {
          float v = acc[am][nt][reg] + bcol[nt];
          if (RELU) v = fmaxf(v, 0.f);
          T[(rbase + reg) * 268 + col] = (__bf16)v;
        }
      }
    }
    __syncthreads();
    int rr = tid >> 2, s4 = (tid & 3) * 64;
    const __bf16* srcp = T + rr * 268 + s4;
    __bf16* dstp = OutE + (size_t)(row0 + p * 128 + rr) * DIM + col0 + s4;
#pragma unroll
    for (int i = 0; i < 8; i++)
      *(bf16x8*)(dstp + i * 8) = *(const bf16x8*)(srcp + i * 8);
  }
}

// ---------------- combine: out[t] = x[t] + sum_k w_k * y[pos_k] ----------------
__global__ __launch_bounds__(256) void combine_kernel(
    const float* __restrict__ x, const __bf16* __restrict__ ybuf,
    const int* __restrict__ pos, const float* __restrict__ rwv,
    float* __restrict__ out) {
  int t = blockIdx.x;
  int tid = threadIdx.x;
  int c = tid * 8;
  int p0 = pos[t * 2 + 0], p1 = pos[t * 2 + 1];
  float w0 = rwv[t * 2 + 0], w1 = rwv[t * 2 + 1];
  const float* xr = x + (size_t)t * DIM + c;
  float4 v0 = *(const float4*)(xr);
  float4 v1 = *(const float4*)(xr + 4);
  float o[8] = {v0.x, v0.y, v0.z, v0.w, v1.x, v1.y, v1.z, v1.w};
  if (p0 >= 0) {
    bf16x8 y = *(const bf16x8*)(ybuf + (size_t)p0 * ODIM + c);
#pragma unroll
    for (int i = 0; i < 8; i++) o[i] += w0 * (float)y[i];
  }
  if (p1 >= 0) {
    bf16x8 y = *(const bf16x8*)(ybuf + (size_t)p1 * ODIM + c);
#pragma unroll
    for (int i = 0; i < 8; i++) o[i] += w1 * (float)y[i];
  }
  float* orow = out + (size_t)t * ODIM + c;
  *(float4*)(orow) = make_float4(o[0], o[1], o[2], o[3]);
  *(float4*)(orow + 4) = make_float4(o[4], o[5], o[6], o[7]);
}

extern "C" void kernel_launch(void* const* d_in, const int* in_sizes, int n_in,
                              void* d_out, int out_size, void* d_ws, size_t ws_size,
                              hipStream_t stream) {
  const float* x = (const float*)d_in[0];
  const float* gate_w = (const float*)d_in[1];
  const float* gate_b = (const float*)d_in[2];
  const float* temp = (const float*)d_in[3];
  const float* w1 = (const float*)d_in[4];
  const float* b1 = (const float*)d_in[5];
  const float* w2 = (const float*)d_in[6];
  const float* b2 = (const float*)d_in[7];
  float* out = (float*)d_out;

  char* ws = (char*)d_ws;
  size_t off = 0;
  float* probs = (float*)(ws + off); off += (size_t)N_TOK * NEXP * 4;
  int* sel = (int*)(ws + off);       off += (size_t)N_TOK * 2 * 4;
  float* rwv = (float*)(ws + off);   off += (size_t)N_TOK * 2 * 4;
  int* cnt_assign = (int*)(ws + off); off += 64;
  int* list_cnt = (int*)(ws + off);   off += 64;
  int* etok = (int*)(ws + off);      off += (size_t)NEXP * CAPACITY * 4;
  int* pos = (int*)(ws + off);       off += (size_t)N_TOK * 2 * 4;
  off = (off + 255) & ~(size_t)255;
  __bf16* xb = (__bf16*)(ws + off);   off += (size_t)N_TOK * DIM * 2;            // 33.5 MB
  ushort* wt_all = (ushort*)(ws + off); off += (size_t)16 * 2048 * 2048 * 2;     // 134 MB
  __bf16* hbuf = (__bf16*)(ws + off); off += (size_t)NEXP * CAPACITY * HDIM * 2; // 84 MB
  // ybuf (84 MB) aliases xb (33.5 MB) + w1t (first 67 MB of wt_all) — both dead
  // after ffn1. ffn2 reads only w2t (second half of wt_all) + hbuf.
  __bf16* ybuf = xb;

  router_kernel<<<N_TOK, 64, 0, stream>>>(x, gate_w, gate_b, temp, probs, sel, rwv, xb);
  float* aux_out = out + (size_t)N_TOK * ODIM;
  aux_kernel<<<1, 256, 0, stream>>>(probs, sel, aux_out, cnt_assign, list_cnt);
  dim3 tgrid(32, 32, 16);
  transpose_cvt_kernel<<<tgrid, 256, 0, stream>>>(w1, w2, wt_all);
  build_lists<<<(N_TOK * 2 + 255) / 256, 256, 0, stream>>>(sel, rwv, cnt_assign,
                                                           list_cnt, etok, pos);
  const __bf16* w1t = (const __bf16*)wt_all;
  const __bf16* w2t = (const __bf16*)(wt_all + (size_t)8 * 2048 * 2048);
  // grid: 10 row-blocks x 8 col-blocks x 8 experts = 640 (multiple of 8 XCDs)
  mfma_ffn_8ph<true, true><<<640, 512, 0, stream>>>(xb, w1t, b1, etok, list_cnt, hbuf);
  mfma_ffn_8ph<false, false><<<640, 512, 0, stream>>>(hbuf, w2t, b2, etok, list_cnt, ybuf);
  combine_kernel<<<N_TOK, 256, 0, stream>>>(x, ybuf, pos, rwv, out);
}